// Round 6
// baseline (1314.094 us; speedup 1.0000x reference)
//
#include <hip/hip_runtime.h>

#define NPART 1024
#define NF    104      // 8 (tp0) + 32 (tp1) + 32 (tp2) + 32 (tp3)
#define RSS   105      // rs stride (odd -> 2-way banking max)
#define CMS   123      // cm stride (odd); pads LDS total to 55040 B -> 2 blocks/CU
                       // -> backend VGPR budget 128 (r1..r5 empirical rule)

__device__ __forceinline__ float softplus_f(float v) {
    return __logf(1.0f + __expf(v));
}

// ---------------------------------------------------------------------------
// Fused pairwise kernel. Tile 32 rows x 64 cols, block 512 thr (8 waves).
// lane l = col; wave w (0..7); k-step 0..3: r = (l + 4w + k) & 31.
// r5 falsified the spill theory: bottleneck was per-iteration weight loads
// (global/scalar, ~150-300 cyc exposed latency each, ~1150/wave-step).
// Fix: stage ALL tp weights in LDS (wl, 9.6 KB) once per block; inner loops
// read them as ds_read_b128 broadcasts (uniform addr + imm offset, in-order
// lgkmcnt, no vmcnt in the loop at all).
// ---------------------------------------------------------------------------
__global__ __launch_bounds__(512) void pair_kernel(
    const float* __restrict__ x,
    const float* __restrict__ tw0, const float* __restrict__ tb0,
    const float* __restrict__ tw,  const float* __restrict__ tb,
    float* __restrict__ Srow,      // [1024][NF] means (pre-zeroed)
    float* __restrict__ Scol)      // [1024][NF] means (pre-zeroed)
{
    __shared__ float4 xs[32];          // 512 B
    __shared__ float rs[32][RSS];      // 13440 B
    __shared__ float cm[64][CMS];      // 31488 B
    __shared__ float4 wl[600];         // 9600 B; float4 units:
    //   [0,64)    tw0 (8x32)      [64,72)   tb0
    //   [72,328)  tw layer2 (32x32) [328,336) tb layer2
    //   [336,592) tw layer3 (32x32) [592,600) tb layer3

    const int t = threadIdx.x;          // 0..511
    const int l = t & 63;               // lane = col within tile
    const int w = t >> 6;               // wave: 0..7
    const int i0 = blockIdx.x * 32;
    const int j  = blockIdx.y * 64 + l;

    for (int idx = t; idx < 32 * RSS; idx += 512) ((float*)rs)[idx] = 0.0f;
    for (int idx = t; idx < 64 * CMS; idx += 512) ((float*)cm)[idx] = 0.0f;
    for (int idx = t; idx < 600; idx += 512) {
        float4 v;
        if      (idx <  64) v = ((const float4*)tw0)[idx];
        else if (idx <  72) v = ((const float4*)tb0)[idx - 64];
        else if (idx < 328) v = ((const float4*)tw)[idx - 72];
        else if (idx < 336) v = ((const float4*)tb)[idx - 328];
        else if (idx < 592) v = ((const float4*)(tw + 1024))[idx - 336];
        else                v = ((const float4*)(tb + 32))[idx - 592];
        wl[idx] = v;
    }
    if (t < 32) {
        xs[t] = make_float4(x[(i0 + t) * 3 + 0], x[(i0 + t) * 3 + 1],
                            x[(i0 + t) * 3 + 2], 0.0f);
    }
    __syncthreads();

    const float xj0 = x[j * 3 + 0];
    const float xj1 = x[j * 3 + 1];
    const float xj2 = x[j * 3 + 2];
    const float A = 0.62831853071795864769f;   // 2*pi / L, L = 10

    #pragma unroll 1
    for (int k = 0; k < 4; ++k) {
        const int r = (l + 4 * w + k) & 31;

        float4 xi = xs[r];
        float dx0 = xi.x - xj0;
        float dx1 = xi.y - xj1;
        float dx2 = xi.z - xj2;
        float s0 = __sinf(A * dx0), s1 = __sinf(A * dx1), s2 = __sinf(A * dx2);
        float c0 = __cosf(A * dx0), c1 = __cosf(A * dx1), c2 = __cosf(A * dx2);
        float mask = (i0 + r == j) ? 0.0f : 1.0f;
        float dsn = mask * sqrtf(s0 * s0 + s1 * s1 + s2 * s2);
        float dcs = mask * sqrtf(c0 * c0 + c1 * c1 + c2 * c2);
        float f0[8] = {c0, c1, c2, s0, s1, s2, dsn, dcs};

        #pragma unroll
        for (int q = 0; q < 8; ++q) {
            atomicAdd(&rs[r][q], f0[q]);      // ds_add_f32
            atomicAdd(&cm[l][q], f0[q]);
        }

        // ---- layer 1: 8 -> 32  (weights from LDS, ds_read_b128 broadcast)
        float4 acc[8];
        #pragma unroll
        for (int o4 = 0; o4 < 8; ++o4) acc[o4] = wl[64 + o4];
        #pragma unroll
        for (int kk = 0; kk < 8; ++kk) {
            const float tv = f0[kk];
            #pragma unroll
            for (int o4 = 0; o4 < 8; ++o4) {
                float4 wv = wl[kk * 8 + o4];
                acc[o4].x = fmaf(tv, wv.x, acc[o4].x);
                acc[o4].y = fmaf(tv, wv.y, acc[o4].y);
                acc[o4].z = fmaf(tv, wv.z, acc[o4].z);
                acc[o4].w = fmaf(tv, wv.w, acc[o4].w);
            }
        }
        float tp[32];
        #pragma unroll
        for (int o4 = 0; o4 < 8; ++o4) {
            tp[4 * o4 + 0] = softplus_f(acc[o4].x);
            tp[4 * o4 + 1] = softplus_f(acc[o4].y);
            tp[4 * o4 + 2] = softplus_f(acc[o4].z);
            tp[4 * o4 + 3] = softplus_f(acc[o4].w);
        }
        #pragma unroll
        for (int o = 0; o < 32; ++o) {
            atomicAdd(&rs[r][8 + o], tp[o]);
            atomicAdd(&cm[l][8 + o], tp[o]);
        }

        // ---- layer 2: 32 -> 32, residual
        #pragma unroll
        for (int o4 = 0; o4 < 8; ++o4) acc[o4] = wl[328 + o4];
        #pragma unroll
        for (int kk = 0; kk < 32; ++kk) {
            const float tv = tp[kk];
            #pragma unroll
            for (int o4 = 0; o4 < 8; ++o4) {
                float4 wv = wl[72 + kk * 8 + o4];
                acc[o4].x = fmaf(tv, wv.x, acc[o4].x);
                acc[o4].y = fmaf(tv, wv.y, acc[o4].y);
                acc[o4].z = fmaf(tv, wv.z, acc[o4].z);
                acc[o4].w = fmaf(tv, wv.w, acc[o4].w);
            }
        }
        #pragma unroll
        for (int o4 = 0; o4 < 8; ++o4) {
            tp[4 * o4 + 0] += softplus_f(acc[o4].x);
            tp[4 * o4 + 1] += softplus_f(acc[o4].y);
            tp[4 * o4 + 2] += softplus_f(acc[o4].z);
            tp[4 * o4 + 3] += softplus_f(acc[o4].w);
        }
        #pragma unroll
        for (int o = 0; o < 32; ++o) {
            atomicAdd(&rs[r][40 + o], tp[o]);
            atomicAdd(&cm[l][40 + o], tp[o]);
        }

        // ---- layer 3: 32 -> 32, residual
        #pragma unroll
        for (int o4 = 0; o4 < 8; ++o4) acc[o4] = wl[592 + o4];
        #pragma unroll
        for (int kk = 0; kk < 32; ++kk) {
            const float tv = tp[kk];
            #pragma unroll
            for (int o4 = 0; o4 < 8; ++o4) {
                float4 wv = wl[336 + kk * 8 + o4];
                acc[o4].x = fmaf(tv, wv.x, acc[o4].x);
                acc[o4].y = fmaf(tv, wv.y, acc[o4].y);
                acc[o4].z = fmaf(tv, wv.z, acc[o4].z);
                acc[o4].w = fmaf(tv, wv.w, acc[o4].w);
            }
        }
        #pragma unroll
        for (int o4 = 0; o4 < 8; ++o4) {
            tp[4 * o4 + 0] += softplus_f(acc[o4].x);
            tp[4 * o4 + 1] += softplus_f(acc[o4].y);
            tp[4 * o4 + 2] += softplus_f(acc[o4].z);
            tp[4 * o4 + 3] += softplus_f(acc[o4].w);
        }
        #pragma unroll
        for (int o = 0; o < 32; ++o) {
            atomicAdd(&rs[r][72 + o], tp[o]);
            atomicAdd(&cm[l][72 + o], tp[o]);
        }
    }

    __syncthreads();
    const float sc = 1.0f / 1024.0f;
    for (int idx = t; idx < 32 * NF; idx += 512) {
        int rr = idx / NF, f = idx - rr * NF;
        atomicAdd(&Srow[(i0 + rr) * NF + f], rs[rr][f] * sc);
    }
    for (int idx = t; idx < 64 * NF; idx += 512) {
        int cc = idx / NF, f = idx - cc * NF;
        atomicAdd(&Scol[(blockIdx.y * 64 + cc) * NF + f], cm[cc][f] * sc);
    }
}

// layer 0: sp=0 so only tp0 mean features (W0 rows 9..24) contribute.
// Also emits up/dn partial sums of the produced sp into sums_out[0:64|64:128].
__global__ __launch_bounds__(256) void sp_layer0_kernel(
    const float* __restrict__ w0, const float* __restrict__ b0,
    const float* __restrict__ Srow, const float* __restrict__ Scol,
    float* __restrict__ sp, float* __restrict__ sums_out)
{
    int t = threadIdx.x;
    int r = blockIdx.x * 4 + (t >> 6);
    int o = t & 63;
    float a = b0[o];
    #pragma unroll
    for (int k = 0; k < 8; ++k) a = fmaf(Srow[r * NF + k], w0[(9 + k) * 64 + o], a);
    #pragma unroll
    for (int k = 0; k < 8; ++k) a = fmaf(Scol[r * NF + k], w0[(17 + k) * 64 + o], a);
    float v = softplus_f(a);
    sp[r * 64 + o] = v;
    atomicAdd(&sums_out[(r < 512 ? 0 : 64) + o], v);
}

// layers 1,2: sp_out = sp_in + softplus([sp,up,dn,trow,tcol] @ W + b).
// uvec (bias + up/dn-mean contributions) computed per block from sums_in.
__global__ __launch_bounds__(256) void sp_layer_kernel(
    const float* __restrict__ spin, const float* __restrict__ W,
    const float* __restrict__ b, const float* __restrict__ sums_in,
    const float* __restrict__ Srow, const float* __restrict__ Scol,
    int F0, float* __restrict__ spout, float* __restrict__ sums_out)
{
    __shared__ float uv[64];
    int t = threadIdx.x;
    int o = t & 63;
    if (t < 64) {
        const float ns = 1.0f / 512.0f;
        float a2 = b[t];
        #pragma unroll 8
        for (int k = 0; k < 64; ++k) a2 = fmaf(sums_in[k] * ns, W[(64 + k) * 64 + t], a2);
        #pragma unroll 8
        for (int k = 0; k < 64; ++k) a2 = fmaf(sums_in[64 + k] * ns, W[(128 + k) * 64 + t], a2);
        uv[t] = a2;
    }
    __syncthreads();
    int r = blockIdx.x * 4 + (t >> 6);
    float a = uv[o];
    const float* sprow = spin + r * 64;
    #pragma unroll 8
    for (int k = 0; k < 64; ++k) a = fmaf(sprow[k], W[k * 64 + o], a);
    #pragma unroll 8
    for (int k = 0; k < 32; ++k) a = fmaf(Srow[r * NF + F0 + k], W[(192 + k) * 64 + o], a);
    #pragma unroll 8
    for (int k = 0; k < 32; ++k) a = fmaf(Scol[r * NF + F0 + k], W[(224 + k) * 64 + o], a);
    float v = sprow[o] + softplus_f(a);
    spout[r * 64 + o] = v;
    atomicAdd(&sums_out[(r < 512 ? 0 : 64) + o], v);
}

// final layer + fin projection + residual x
__global__ __launch_bounds__(256) void sp_final_kernel(
    const float* __restrict__ spin, const float* __restrict__ W,
    const float* __restrict__ b, const float* __restrict__ sums_in,
    const float* __restrict__ Srow, const float* __restrict__ Scol,
    const float* __restrict__ x, const float* __restrict__ finw, const float* __restrict__ finb,
    float* __restrict__ out)
{
    __shared__ float uv[64];
    __shared__ float sb[4][64];
    int t = threadIdx.x;
    int ty = t >> 6, o = t & 63;
    if (t < 64) {
        const float ns = 1.0f / 512.0f;
        float a2 = b[t];
        #pragma unroll 8
        for (int k = 0; k < 64; ++k) a2 = fmaf(sums_in[k] * ns, W[(64 + k) * 64 + t], a2);
        #pragma unroll 8
        for (int k = 0; k < 64; ++k) a2 = fmaf(sums_in[64 + k] * ns, W[(128 + k) * 64 + t], a2);
        uv[t] = a2;
    }
    __syncthreads();
    int r = blockIdx.x * 4 + ty;
    float a = uv[o];
    const float* sprow = spin + r * 64;
    #pragma unroll 8
    for (int k = 0; k < 64; ++k) a = fmaf(sprow[k], W[k * 64 + o], a);
    #pragma unroll 8
    for (int k = 0; k < 32; ++k) a = fmaf(Srow[r * NF + 72 + k], W[(192 + k) * 64 + o], a);
    #pragma unroll 8
    for (int k = 0; k < 32; ++k) a = fmaf(Scol[r * NF + 72 + k], W[(224 + k) * 64 + o], a);
    sb[ty][o] = sprow[o] + softplus_f(a);
    __syncthreads();
    if (t < 12) {
        int rr = t / 3, d = t - rr * 3;
        int row = blockIdx.x * 4 + rr;
        float acc = x[row * 3 + d] + finb[d];
        #pragma unroll
        for (int k = 0; k < 64; ++k) acc = fmaf(sb[rr][k], finw[k * 3 + d], acc);
        out[row * 3 + d] = acc;
    }
}

extern "C" void kernel_launch(void* const* d_in, const int* in_sizes, int n_in,
                              void* d_out, int out_size, void* d_ws, size_t ws_size,
                              hipStream_t stream)
{
    (void)in_sizes; (void)n_in; (void)out_size; (void)ws_size;
    const float* x     = (const float*)d_in[0];
    const float* sp_w0 = (const float*)d_in[1];
    const float* sp_b0 = (const float*)d_in[2];
    const float* sp_w  = (const float*)d_in[3];
    const float* sp_b  = (const float*)d_in[4];
    const float* tp_w0 = (const float*)d_in[5];
    const float* tp_b0 = (const float*)d_in[6];
    const float* tp_w  = (const float*)d_in[7];
    const float* tp_b  = (const float*)d_in[8];
    const float* fin_w = (const float*)d_in[9];
    const float* fin_b = (const float*)d_in[10];
    float* out = (float*)d_out;
    float* ws  = (float*)d_ws;

    float* Srow  = ws;                      // 1024*NF (means)
    float* Scol  = Srow + NPART * NF;       // 1024*NF (means)
    float* sums0 = Scol + NPART * NF;       // 128 (up|dn sums after layer0)
    float* sums1 = sums0 + 128;             // 128
    float* sums2 = sums1 + 128;             // 128
    float* spA   = sums2 + 128;             // 1024*64
    float* spB   = spA + NPART * 64;        // 1024*64
    float* spC   = spB + NPART * 64;        // 1024*64

    // zero Srow, Scol, sums0..2 in one memset
    hipMemsetAsync(Srow, 0, (2 * NPART * NF + 384) * sizeof(float), stream);

    pair_kernel<<<dim3(32, 16), 512, 0, stream>>>(x, tp_w0, tp_b0, tp_w, tp_b, Srow, Scol);
    sp_layer0_kernel<<<256, 256, 0, stream>>>(sp_w0, sp_b0, Srow, Scol, spA, sums0);
    sp_layer_kernel<<<256, 256, 0, stream>>>(spA, sp_w + 0 * 256 * 64, sp_b + 0 * 64,
                                             sums0, Srow, Scol, 8, spB, sums1);
    sp_layer_kernel<<<256, 256, 0, stream>>>(spB, sp_w + 1 * 256 * 64, sp_b + 1 * 64,
                                             sums1, Srow, Scol, 40, spC, sums2);
    sp_final_kernel<<<256, 256, 0, stream>>>(spC, sp_w + 2 * 256 * 64, sp_b + 2 * 64,
                                             sums2, Srow, Scol, x, fin_w, fin_b, out);
}

// Round 7
// 397.267 us; speedup vs baseline: 3.3078x; 3.3078x over previous
//
#include <hip/hip_runtime.h>

#define NPART 1024
#define NF    104      // 8 (tp0) + 32 (tp1) + 32 (tp2) + 32 (tp3)

typedef __attribute__((ext_vector_type(8))) short short8;   // 8 bf16 (4 VGPRs)
typedef __attribute__((ext_vector_type(4))) float floatx4;  // MFMA C/D

__device__ __forceinline__ float softplus_f(float v) {
    return __logf(1.0f + __expf(v));
}
__device__ __forceinline__ unsigned short f2bf(float f) {
    union { float f; unsigned u; } v; v.f = f;
    unsigned r = v.u + 0x7FFFu + ((v.u >> 16) & 1u);   // RNE
    return (unsigned short)(r >> 16);
}
__device__ __forceinline__ unsigned pk2(float a, float b) {
    return (unsigned)f2bf(a) | ((unsigned)f2bf(b) << 16);
}

// ---------------------------------------------------------------------------
// MFMA pair kernel. Weights live in VGPRs as B-fragments for the whole kernel
// (r2-r6 lesson: ANY per-iteration weight streaming path serializes).
// Block 256 thr = 4 waves. Block tile: 64 i x 32 j. Wave w: i in [i0+16w,+16).
// Iter s=0..7: lane (m=lane&15, q=lane>>4) handles pair (i=ib+m, j=j0+4s+q).
// MFMA tiles: mt=0..3 <-> j=j0+4s+mt, M=16 i's, N=32 feats (even/odd split:
// nt tile col n holds feature 2n+nt so staging packs to b32).
// Layouts (HW-verified): C col=lane&15,row=quad*4+reg; A[m=lane&15][k=quad*8+j].
// B assumed symmetric: lane n=lane&15 holds B[k=quad*8+e][n].
// Row sums: registers (lane's (i,feat) iteration-invariant), flushed once.
// Col sums: LDS 4-way ds_add per tile, flushed at block end.
// ---------------------------------------------------------------------------
__global__ __launch_bounds__(256) void pair_kernel(
    const float* __restrict__ x,
    const float* __restrict__ tw0, const float* __restrict__ tb0,
    const float* __restrict__ tw,  const float* __restrict__ tb,
    float* __restrict__ Srow,      // [1024][NF] means (pre-zeroed)
    float* __restrict__ Scol)      // [1024][NF] means (pre-zeroed)
{
    __shared__ unsigned f0buf[4][288];   // per wave: 4 tiles x 16 rows x 8 bf16 (+pad)
    __shared__ unsigned tpbuf[4][1280];  // per wave: 4 tiles x 16 rows x 40 bf16 (stride 20 uints)
    __shared__ float    cmb[32][146];    // col sums [j-local][feat] (+LDS pad for occupancy)
    __shared__ float4   xjs[32];

    const int t    = threadIdx.x;
    const int w    = t >> 6;
    const int lane = t & 63;
    const int m    = lane & 15;          // A-row / C-col / B-col index
    const int q    = lane >> 4;          // quad: A/B k-slice, C row-group
    const int i0   = blockIdx.x * 64;
    const int j0   = blockIdx.y * 32;
    const int ib   = i0 + w * 16;
    const int im   = ib + m;

    for (int idx = t; idx < 4 * 288; idx += 256) ((unsigned*)f0buf)[idx] = 0u;
    for (int idx = t; idx < 32 * 146; idx += 256) ((float*)cmb)[idx] = 0.0f;
    if (t < 32) {
        int j = j0 + t;
        xjs[t] = make_float4(x[j * 3], x[j * 3 + 1], x[j * 3 + 2], 0.0f);
    }

    // --- persistent B-fragments + biases (loaded once; ~24 VGPRs) ---
    short8 B1[2], B2[2], B3[2];
    float bias1[2], bias2[2], bias3[2];
    #pragma unroll
    for (int nt = 0; nt < 2; ++nt) {
        const int fc = 2 * m + nt;               // global feature column
        bias1[nt] = tb0[fc]; bias2[nt] = tb[fc]; bias3[nt] = tb[32 + fc];
        #pragma unroll
        for (int e = 0; e < 8; ++e) {
            const int k = q * 8 + e;
            B1[nt][e] = (k < 8) ? (short)f2bf(tw0[k * 32 + fc]) : (short)0;
            B2[nt][e] = (short)f2bf(tw[k * 32 + fc]);
            B3[nt][e] = (short)f2bf(tw[1024 + k * 32 + fc]);
        }
    }
    const float xi0 = x[im * 3], xi1 = x[im * 3 + 1], xi2 = x[im * 3 + 2];

    float rowacc1[2][4] = {{0.f,0.f,0.f,0.f},{0.f,0.f,0.f,0.f}};
    float rowacc2[2][4] = {{0.f,0.f,0.f,0.f},{0.f,0.f,0.f,0.f}};
    float rowacc3[2][4] = {{0.f,0.f,0.f,0.f},{0.f,0.f,0.f,0.f}};
    float f0row[8] = {0.f,0.f,0.f,0.f,0.f,0.f,0.f,0.f};

    __syncthreads();

    const float A = 0.62831853071795864769f;     // 2*pi / L, L = 10
    const floatx4 zero = {0.f, 0.f, 0.f, 0.f};

    #pragma unroll 1
    for (int s = 0; s < 8; ++s) {
        const int jj = 4 * s + q;                // j-local of this lane's pair
        float4 xj = xjs[jj];
        float dx0 = xi0 - xj.x, dx1 = xi1 - xj.y, dx2 = xi2 - xj.z;
        float s0 = __sinf(A * dx0), s1 = __sinf(A * dx1), s2 = __sinf(A * dx2);
        float c0 = __cosf(A * dx0), c1 = __cosf(A * dx1), c2 = __cosf(A * dx2);
        float mask = (im == j0 + jj) ? 0.0f : 1.0f;
        float dsn = mask * sqrtf(s0 * s0 + s1 * s1 + s2 * s2);
        float dcs = mask * sqrtf(c0 * c0 + c1 * c1 + c2 * c2);
        float f0[8] = {c0, c1, c2, s0, s1, s2, dsn, dcs};

        #pragma unroll
        for (int e = 0; e < 8; ++e) {
            f0row[e] += f0[e];
            atomicAdd(&cmb[jj][e], f0[e]);       // 16-way same-address, 8 ops
        }
        // stage f0 (bf16) for A-frags: f0buf[w][tile=q][row=m]
        *(uint4*)&f0buf[w][(q * 16 + m) * 4] =
            make_uint4(pk2(f0[0], f0[1]), pk2(f0[2], f0[3]),
                       pk2(f0[4], f0[5]), pk2(f0[6], f0[7]));

        float tp[4][2][4];
        // ---- layer 1 (K=8 zero-padded to 32; B1 rows >=8 are zero) ----
        #pragma unroll
        for (int mt = 0; mt < 4; ++mt) {
            short8 a = *(const short8*)((const unsigned*)&f0buf[w][0] + (mt * 16 + m) * 4 + 4 * q);
            #pragma unroll
            for (int nt = 0; nt < 2; ++nt) {
                floatx4 c = __builtin_amdgcn_mfma_f32_16x16x32_bf16(a, B1[nt], zero, 0, 0, 0);
                float colp = 0.f;
                #pragma unroll
                for (int r = 0; r < 4; ++r) {
                    float v = softplus_f(c[r] + bias1[nt]);
                    tp[mt][nt][r] = v;
                    rowacc1[nt][r] += v;
                    colp += v;
                }
                atomicAdd(&cmb[4 * s + mt][8 + 2 * m + nt], colp);
            }
            #pragma unroll
            for (int r = 0; r < 4; ++r)
                tpbuf[w][(mt * 16 + q * 4 + r) * 20 + m] = pk2(tp[mt][0][r], tp[mt][1][r]);
        }
        // ---- layer 2 (residual) ----
        #pragma unroll
        for (int mt = 0; mt < 4; ++mt) {
            short8 a = *(const short8*)(&tpbuf[w][(mt * 16 + m) * 20 + 4 * q]);
            #pragma unroll
            for (int nt = 0; nt < 2; ++nt) {
                floatx4 c = __builtin_amdgcn_mfma_f32_16x16x32_bf16(a, B2[nt], zero, 0, 0, 0);
                float colp = 0.f;
                #pragma unroll
                for (int r = 0; r < 4; ++r) {
                    float v = tp[mt][nt][r] + softplus_f(c[r] + bias2[nt]);
                    tp[mt][nt][r] = v;
                    rowacc2[nt][r] += v;
                    colp += v;
                }
                atomicAdd(&cmb[4 * s + mt][40 + 2 * m + nt], colp);
            }
            #pragma unroll
            for (int r = 0; r < 4; ++r)
                tpbuf[w][(mt * 16 + q * 4 + r) * 20 + m] = pk2(tp[mt][0][r], tp[mt][1][r]);
        }
        // ---- layer 3 (residual, no staging out) ----
        #pragma unroll
        for (int mt = 0; mt < 4; ++mt) {
            short8 a = *(const short8*)(&tpbuf[w][(mt * 16 + m) * 20 + 4 * q]);
            #pragma unroll
            for (int nt = 0; nt < 2; ++nt) {
                floatx4 c = __builtin_amdgcn_mfma_f32_16x16x32_bf16(a, B3[nt], zero, 0, 0, 0);
                float colp = 0.f;
                #pragma unroll
                for (int r = 0; r < 4; ++r) {
                    float v = tp[mt][nt][r] + softplus_f(c[r] + bias3[nt]);
                    rowacc3[nt][r] += v;
                    colp += v;
                }
                atomicAdd(&cmb[4 * s + mt][72 + 2 * m + nt], colp);
            }
        }
    }

    // ---- flush row sums (register accumulators -> global atomics, once) ----
    const float sc = 1.0f / 1024.0f;
    #pragma unroll
    for (int e = 0; e < 8; ++e)
        atomicAdd(&Srow[im * NF + e], f0row[e] * sc);
    #pragma unroll
    for (int nt = 0; nt < 2; ++nt) {
        #pragma unroll
        for (int r = 0; r < 4; ++r) {
            const int i = ib + q * 4 + r;
            atomicAdd(&Srow[i * NF + 8  + 2 * m + nt], rowacc1[nt][r] * sc);
            atomicAdd(&Srow[i * NF + 40 + 2 * m + nt], rowacc2[nt][r] * sc);
            atomicAdd(&Srow[i * NF + 72 + 2 * m + nt], rowacc3[nt][r] * sc);
        }
    }
    __syncthreads();
    // ---- flush col sums ----
    for (int idx = t; idx < 32 * NF; idx += 256) {
        int jj = idx / NF, f = idx - jj * NF;
        atomicAdd(&Scol[(j0 + jj) * NF + f], cmb[jj][f] * sc);
    }
}

// layer 0: sp=0 so only tp0 mean features (W0 rows 9..24) contribute.
__global__ __launch_bounds__(256) void sp_layer0_kernel(
    const float* __restrict__ w0, const float* __restrict__ b0,
    const float* __restrict__ Srow, const float* __restrict__ Scol,
    float* __restrict__ sp, float* __restrict__ sums_out)
{
    int t = threadIdx.x;
    int r = blockIdx.x * 4 + (t >> 6);
    int o = t & 63;
    float a = b0[o];
    #pragma unroll
    for (int k = 0; k < 8; ++k) a = fmaf(Srow[r * NF + k], w0[(9 + k) * 64 + o], a);
    #pragma unroll
    for (int k = 0; k < 8; ++k) a = fmaf(Scol[r * NF + k], w0[(17 + k) * 64 + o], a);
    float v = softplus_f(a);
    sp[r * 64 + o] = v;
    atomicAdd(&sums_out[(r < 512 ? 0 : 64) + o], v);
}

// layers 1,2: sp_out = sp_in + softplus([sp,up,dn,trow,tcol] @ W + b).
__global__ __launch_bounds__(256) void sp_layer_kernel(
    const float* __restrict__ spin, const float* __restrict__ W,
    const float* __restrict__ b, const float* __restrict__ sums_in,
    const float* __restrict__ Srow, const float* __restrict__ Scol,
    int F0, float* __restrict__ spout, float* __restrict__ sums_out)
{
    __shared__ float uv[64];
    int t = threadIdx.x;
    int o = t & 63;
    if (t < 64) {
        const float ns = 1.0f / 512.0f;
        float a2 = b[t];
        #pragma unroll 8
        for (int k = 0; k < 64; ++k) a2 = fmaf(sums_in[k] * ns, W[(64 + k) * 64 + t], a2);
        #pragma unroll 8
        for (int k = 0; k < 64; ++k) a2 = fmaf(sums_in[64 + k] * ns, W[(128 + k) * 64 + t], a2);
        uv[t] = a2;
    }
    __syncthreads();
    int r = blockIdx.x * 4 + (t >> 6);
    float a = uv[o];
    const float* sprow = spin + r * 64;
    #pragma unroll 8
    for (int k = 0; k < 64; ++k) a = fmaf(sprow[k], W[k * 64 + o], a);
    #pragma unroll 8
    for (int k = 0; k < 32; ++k) a = fmaf(Srow[r * NF + F0 + k], W[(192 + k) * 64 + o], a);
    #pragma unroll 8
    for (int k = 0; k < 32; ++k) a = fmaf(Scol[r * NF + F0 + k], W[(224 + k) * 64 + o], a);
    float v = sprow[o] + softplus_f(a);
    spout[r * 64 + o] = v;
    atomicAdd(&sums_out[(r < 512 ? 0 : 64) + o], v);
}

// final layer + fin projection + residual x
__global__ __launch_bounds__(256) void sp_final_kernel(
    const float* __restrict__ spin, const float* __restrict__ W,
    const float* __restrict__ b, const float* __restrict__ sums_in,
    const float* __restrict__ Srow, const float* __restrict__ Scol,
    const float* __restrict__ x, const float* __restrict__ finw, const float* __restrict__ finb,
    float* __restrict__ out)
{
    __shared__ float uv[64];
    __shared__ float sb[4][64];
    int t = threadIdx.x;
    int ty = t >> 6, o = t & 63;
    if (t < 64) {
        const float ns = 1.0f / 512.0f;
        float a2 = b[t];
        #pragma unroll 8
        for (int k = 0; k < 64; ++k) a2 = fmaf(sums_in[k] * ns, W[(64 + k) * 64 + t], a2);
        #pragma unroll 8
        for (int k = 0; k < 64; ++k) a2 = fmaf(sums_in[64 + k] * ns, W[(128 + k) * 64 + t], a2);
        uv[t] = a2;
    }
    __syncthreads();
    int r = blockIdx.x * 4 + ty;
    float a = uv[o];
    const float* sprow = spin + r * 64;
    #pragma unroll 8
    for (int k = 0; k < 64; ++k) a = fmaf(sprow[k], W[k * 64 + o], a);
    #pragma unroll 8
    for (int k = 0; k < 32; ++k) a = fmaf(Srow[r * NF + 72 + k], W[(192 + k) * 64 + o], a);
    #pragma unroll 8
    for (int k = 0; k < 32; ++k) a = fmaf(Scol[r * NF + 72 + k], W[(224 + k) * 64 + o], a);
    sb[ty][o] = sprow[o] + softplus_f(a);
    __syncthreads();
    if (t < 12) {
        int rr = t / 3, d = t - rr * 3;
        int row = blockIdx.x * 4 + rr;
        float acc = x[row * 3 + d] + finb[d];
        #pragma unroll
        for (int k = 0; k < 64; ++k) acc = fmaf(sb[rr][k], finw[k * 3 + d], acc);
        out[row * 3 + d] = acc;
    }
}

extern "C" void kernel_launch(void* const* d_in, const int* in_sizes, int n_in,
                              void* d_out, int out_size, void* d_ws, size_t ws_size,
                              hipStream_t stream)
{
    (void)in_sizes; (void)n_in; (void)out_size; (void)ws_size;
    const float* x     = (const float*)d_in[0];
    const float* sp_w0 = (const float*)d_in[1];
    const float* sp_b0 = (const float*)d_in[2];
    const float* sp_w  = (const float*)d_in[3];
    const float* sp_b  = (const float*)d_in[4];
    const float* tp_w0 = (const float*)d_in[5];
    const float* tp_b0 = (const float*)d_in[6];
    const float* tp_w  = (const float*)d_in[7];
    const float* tp_b  = (const float*)d_in[8];
    const float* fin_w = (const float*)d_in[9];
    const float* fin_b = (const float*)d_in[10];
    float* out = (float*)d_out;
    float* ws  = (float*)d_ws;

    float* Srow  = ws;                      // 1024*NF (means)
    float* Scol  = Srow + NPART * NF;       // 1024*NF (means)
    float* sums0 = Scol + NPART * NF;       // 128 (up|dn sums after layer0)
    float* sums1 = sums0 + 128;             // 128
    float* sums2 = sums1 + 128;             // 128
    float* spA   = sums2 + 128;             // 1024*64
    float* spB   = spA + NPART * 64;        // 1024*64
    float* spC   = spB + NPART * 64;        // 1024*64

    hipMemsetAsync(Srow, 0, (2 * NPART * NF + 384) * sizeof(float), stream);

    pair_kernel<<<dim3(16, 32), 256, 0, stream>>>(x, tp_w0, tp_b0, tp_w, tp_b, Srow, Scol);
    sp_layer0_kernel<<<256, 256, 0, stream>>>(sp_w0, sp_b0, Srow, Scol, spA, sums0);
    sp_layer_kernel<<<256, 256, 0, stream>>>(spA, sp_w + 0 * 256 * 64, sp_b + 0 * 64,
                                             sums0, Srow, Scol, 8, spB, sums1);
    sp_layer_kernel<<<256, 256, 0, stream>>>(spB, sp_w + 1 * 256 * 64, sp_b + 1 * 64,
                                             sums1, Srow, Scol, 40, spC, sums2);
    sp_final_kernel<<<256, 256, 0, stream>>>(spC, sp_w + 2 * 256 * 64, sp_b + 2 * 64,
                                             sums2, Srow, Scol, x, fin_w, fin_b, out);
}

// Round 8
// 350.739 us; speedup vs baseline: 3.7466x; 1.1327x over previous
//
#include <hip/hip_runtime.h>

#define NPART 1024
#define NF    104      // 8 (tp0) + 32 (tp1) + 32 (tp2) + 32 (tp3)

typedef __attribute__((ext_vector_type(8))) short short8;   // 8 bf16 (4 VGPRs)
typedef __attribute__((ext_vector_type(4))) float floatx4;  // MFMA C/D

__device__ __forceinline__ float softplus_f(float v) {
    return __logf(1.0f + __expf(v));
}
__device__ __forceinline__ unsigned short f2bf(float f) {
    union { float f; unsigned u; } v; v.f = f;
    unsigned r = v.u + 0x7FFFu + ((v.u >> 16) & 1u);   // RNE
    return (unsigned short)(r >> 16);
}
__device__ __forceinline__ unsigned pk2(float a, float b) {
    return (unsigned)f2bf(a) | ((unsigned)f2bf(b) << 16);
}

// ---------------------------------------------------------------------------
// MFMA pair kernel (r7 structure, flush rewritten).
// Block 256 thr = 4 waves. Block tile: 64 i x 32 j. Wave w: i in [i0+16w,+16).
// Iter s=0..7: lane (m=lane&15, q=lane>>4) handles pair (i=ib+m, j=j0+4s+q).
// Weights persist in VGPRs as MFMA B-fragments (r7-verified layouts).
// r7 lesson: the global atomicAdd flush (6M contended RMWs, 64 MB HBM dirty
// traffic) WAS the kernel duration. Now: per-block partial sums stored with
// plain coalesced writes (row partials keyed by j-block, col partials by
// i-block), reduced by reduce_kernel. No global atomics anywhere in this file
// except the tiny 128-wide sp sums.
// ---------------------------------------------------------------------------
__global__ __launch_bounds__(256) void pair_kernel(
    const float* __restrict__ x,
    const float* __restrict__ tw0, const float* __restrict__ tb0,
    const float* __restrict__ tw,  const float* __restrict__ tb,
    float* __restrict__ ws_rs,     // [32 j-blocks][1024 i][NF] partial row sums
    float* __restrict__ ws_cs)     // [16 i-blocks][1024 j][NF] partial col sums
{
    __shared__ unsigned f0buf[4][288];   // per wave: 4 tiles x 16 rows x 4 uints (+pad, zeroed)
    __shared__ unsigned tpbuf[4][1280];  // per wave: 4 tiles x 16 rows x 20 uints
    __shared__ float    cmb[32][146];    // col sums [j-local][feat] (+pad)
    __shared__ float4   xjs[32];

    const int t    = threadIdx.x;
    const int w    = t >> 6;
    const int lane = t & 63;
    const int m    = lane & 15;          // A-row / C-col index
    const int q    = lane >> 4;          // quad: k-slice / C row-group
    const int i0   = blockIdx.x * 64;
    const int j0   = blockIdx.y * 32;
    const int ib   = i0 + w * 16;
    const int im   = ib + m;

    for (int idx = t; idx < 4 * 288; idx += 256) ((unsigned*)f0buf)[idx] = 0u;
    for (int idx = t; idx < 32 * 146; idx += 256) ((float*)cmb)[idx] = 0.0f;
    if (t < 32) {
        int j = j0 + t;
        xjs[t] = make_float4(x[j * 3], x[j * 3 + 1], x[j * 3 + 2], 0.0f);
    }

    // --- persistent B-fragments + biases (loaded once) ---
    short8 B1[2], B2[2], B3[2];
    float bias1[2], bias2[2], bias3[2];
    #pragma unroll
    for (int nt = 0; nt < 2; ++nt) {
        const int fc = 2 * m + nt;               // global feature column
        bias1[nt] = tb0[fc]; bias2[nt] = tb[fc]; bias3[nt] = tb[32 + fc];
        #pragma unroll
        for (int e = 0; e < 8; ++e) {
            const int k = q * 8 + e;
            B1[nt][e] = (k < 8) ? (short)f2bf(tw0[k * 32 + fc]) : (short)0;
            B2[nt][e] = (short)f2bf(tw[k * 32 + fc]);
            B3[nt][e] = (short)f2bf(tw[1024 + k * 32 + fc]);
        }
    }
    const float xi0 = x[im * 3], xi1 = x[im * 3 + 1], xi2 = x[im * 3 + 2];

    float rowacc1[2][4] = {{0.f,0.f,0.f,0.f},{0.f,0.f,0.f,0.f}};
    float rowacc2[2][4] = {{0.f,0.f,0.f,0.f},{0.f,0.f,0.f,0.f}};
    float rowacc3[2][4] = {{0.f,0.f,0.f,0.f},{0.f,0.f,0.f,0.f}};
    float f0row[8] = {0.f,0.f,0.f,0.f,0.f,0.f,0.f,0.f};

    __syncthreads();

    const float A = 0.62831853071795864769f;     // 2*pi / L, L = 10
    const floatx4 zero = {0.f, 0.f, 0.f, 0.f};

    #pragma unroll 1
    for (int s = 0; s < 8; ++s) {
        const int jj = 4 * s + q;                // j-local of this lane's pair
        float4 xj = xjs[jj];
        float dx0 = xi0 - xj.x, dx1 = xi1 - xj.y, dx2 = xi2 - xj.z;
        float s0 = __sinf(A * dx0), s1 = __sinf(A * dx1), s2 = __sinf(A * dx2);
        float c0 = __cosf(A * dx0), c1 = __cosf(A * dx1), c2 = __cosf(A * dx2);
        float mask = (im == j0 + jj) ? 0.0f : 1.0f;
        float dsn = mask * sqrtf(s0 * s0 + s1 * s1 + s2 * s2);
        float dcs = mask * sqrtf(c0 * c0 + c1 * c1 + c2 * c2);
        float f0[8] = {c0, c1, c2, s0, s1, s2, dsn, dcs};

        #pragma unroll
        for (int e = 0; e < 8; ++e) {
            f0row[e] += f0[e];
            atomicAdd(&cmb[jj][e], f0[e]);
        }
        // stage f0 (bf16) for A-frags: f0buf[w][tile=q][row=m]
        *(uint4*)&f0buf[w][(q * 16 + m) * 4] =
            make_uint4(pk2(f0[0], f0[1]), pk2(f0[2], f0[3]),
                       pk2(f0[4], f0[5]), pk2(f0[6], f0[7]));

        float tp[4][2][4];
        // ---- layer 1 (K=8 zero-padded; B1 rows >=8 are zero) ----
        #pragma unroll
        for (int mt = 0; mt < 4; ++mt) {
            short8 a = *(const short8*)((const unsigned*)&f0buf[w][0] + (mt * 16 + m) * 4 + 4 * q);
            #pragma unroll
            for (int nt = 0; nt < 2; ++nt) {
                floatx4 c = __builtin_amdgcn_mfma_f32_16x16x32_bf16(a, B1[nt], zero, 0, 0, 0);
                float colp = 0.f;
                #pragma unroll
                for (int r = 0; r < 4; ++r) {
                    float v = softplus_f(c[r] + bias1[nt]);
                    tp[mt][nt][r] = v;
                    rowacc1[nt][r] += v;
                    colp += v;
                }
                atomicAdd(&cmb[4 * s + mt][8 + 2 * m + nt], colp);
            }
            #pragma unroll
            for (int r = 0; r < 4; ++r)
                tpbuf[w][(mt * 16 + q * 4 + r) * 20 + m] = pk2(tp[mt][0][r], tp[mt][1][r]);
        }
        // ---- layer 2 (residual) ----
        #pragma unroll
        for (int mt = 0; mt < 4; ++mt) {
            short8 a = *(const short8*)(&tpbuf[w][(mt * 16 + m) * 20 + 4 * q]);
            #pragma unroll
            for (int nt = 0; nt < 2; ++nt) {
                floatx4 c = __builtin_amdgcn_mfma_f32_16x16x32_bf16(a, B2[nt], zero, 0, 0, 0);
                float colp = 0.f;
                #pragma unroll
                for (int r = 0; r < 4; ++r) {
                    float v = tp[mt][nt][r] + softplus_f(c[r] + bias2[nt]);
                    tp[mt][nt][r] = v;
                    rowacc2[nt][r] += v;
                    colp += v;
                }
                atomicAdd(&cmb[4 * s + mt][40 + 2 * m + nt], colp);
            }
            #pragma unroll
            for (int r = 0; r < 4; ++r)
                tpbuf[w][(mt * 16 + q * 4 + r) * 20 + m] = pk2(tp[mt][0][r], tp[mt][1][r]);
        }
        // ---- layer 3 (residual, no staging out) ----
        #pragma unroll
        for (int mt = 0; mt < 4; ++mt) {
            short8 a = *(const short8*)(&tpbuf[w][(mt * 16 + m) * 20 + 4 * q]);
            #pragma unroll
            for (int nt = 0; nt < 2; ++nt) {
                floatx4 c = __builtin_amdgcn_mfma_f32_16x16x32_bf16(a, B3[nt], zero, 0, 0, 0);
                float colp = 0.f;
                #pragma unroll
                for (int r = 0; r < 4; ++r) {
                    float v = tp[mt][nt][r] + softplus_f(c[r] + bias3[nt]);
                    rowacc3[nt][r] += v;
                    colp += v;
                }
                atomicAdd(&cmb[4 * s + mt][72 + 2 * m + nt], colp);
            }
        }
    }

    // ---- flush row partials: plain coalesced-ish stores, zero contention ----
    float* rbase = ws_rs + (size_t)blockIdx.y * NPART * NF;
    // f0 row sums: 4 q-lanes duplicate i -> shuffle-reduce over q, store from q==0
    float f0s[8];
    #pragma unroll
    for (int e = 0; e < 8; ++e) {
        float v = f0row[e];
        v += __shfl_xor(v, 16, 64);
        v += __shfl_xor(v, 32, 64);
        f0s[e] = v;
    }
    if (q == 0) {
        #pragma unroll
        for (int e = 0; e < 8; ++e) rbase[im * NF + e] = f0s[e];
    }
    // layer row sums: unique (i, feat) per lane
    #pragma unroll
    for (int nt = 0; nt < 2; ++nt) {
        #pragma unroll
        for (int r = 0; r < 4; ++r) {
            const int i = ib + q * 4 + r;
            rbase[i * NF + 8  + 2 * m + nt] = rowacc1[nt][r];
            rbase[i * NF + 40 + 2 * m + nt] = rowacc2[nt][r];
            rbase[i * NF + 72 + 2 * m + nt] = rowacc3[nt][r];
        }
    }
    __syncthreads();
    // ---- flush col partials ----
    float* cbase = ws_cs + (size_t)blockIdx.x * NPART * NF;
    for (int idx = t; idx < 32 * NF; idx += 256) {
        int jj = idx / NF, f = idx - jj * NF;
        cbase[(j0 + jj) * NF + f] = cmb[jj][f];
    }
}

// Sum partials -> means; also zero the sp up/dn sums buffers (384 floats).
__global__ __launch_bounds__(256) void reduce_kernel(
    const float* __restrict__ ws_rs, const float* __restrict__ ws_cs,
    float* __restrict__ Srow, float* __restrict__ Scol, float* __restrict__ sums)
{
    int idx = blockIdx.x * 256 + threadIdx.x;
    if (idx < 384) sums[idx] = 0.0f;
    if (idx >= NPART * NF) return;
    float a = 0.0f, b = 0.0f;
    #pragma unroll
    for (int s = 0; s < 32; ++s) a += ws_rs[s * NPART * NF + idx];
    #pragma unroll
    for (int s = 0; s < 16; ++s) b += ws_cs[s * NPART * NF + idx];
    const float sc = 1.0f / 1024.0f;
    Srow[idx] = a * sc;
    Scol[idx] = b * sc;
}

// layer 0: sp=0 so only tp0 mean features (W0 rows 9..24) contribute.
__global__ __launch_bounds__(256) void sp_layer0_kernel(
    const float* __restrict__ w0, const float* __restrict__ b0,
    const float* __restrict__ Srow, const float* __restrict__ Scol,
    float* __restrict__ sp, float* __restrict__ sums_out)
{
    int t = threadIdx.x;
    int r = blockIdx.x * 4 + (t >> 6);
    int o = t & 63;
    float a = b0[o];
    #pragma unroll
    for (int k = 0; k < 8; ++k) a = fmaf(Srow[r * NF + k], w0[(9 + k) * 64 + o], a);
    #pragma unroll
    for (int k = 0; k < 8; ++k) a = fmaf(Scol[r * NF + k], w0[(17 + k) * 64 + o], a);
    float v = softplus_f(a);
    sp[r * 64 + o] = v;
    atomicAdd(&sums_out[(r < 512 ? 0 : 64) + o], v);
}

// layers 1,2: sp_out = sp_in + softplus([sp,up,dn,trow,tcol] @ W + b).
__global__ __launch_bounds__(256) void sp_layer_kernel(
    const float* __restrict__ spin, const float* __restrict__ W,
    const float* __restrict__ b, const float* __restrict__ sums_in,
    const float* __restrict__ Srow, const float* __restrict__ Scol,
    int F0, float* __restrict__ spout, float* __restrict__ sums_out)
{
    __shared__ float uv[64];
    int t = threadIdx.x;
    int o = t & 63;
    if (t < 64) {
        const float ns = 1.0f / 512.0f;
        float a2 = b[t];
        #pragma unroll 8
        for (int k = 0; k < 64; ++k) a2 = fmaf(sums_in[k] * ns, W[(64 + k) * 64 + t], a2);
        #pragma unroll 8
        for (int k = 0; k < 64; ++k) a2 = fmaf(sums_in[64 + k] * ns, W[(128 + k) * 64 + t], a2);
        uv[t] = a2;
    }
    __syncthreads();
    int r = blockIdx.x * 4 + (t >> 6);
    float a = uv[o];
    const float* sprow = spin + r * 64;
    #pragma unroll 8
    for (int k = 0; k < 64; ++k) a = fmaf(sprow[k], W[k * 64 + o], a);
    #pragma unroll 8
    for (int k = 0; k < 32; ++k) a = fmaf(Srow[r * NF + F0 + k], W[(192 + k) * 64 + o], a);
    #pragma unroll 8
    for (int k = 0; k < 32; ++k) a = fmaf(Scol[r * NF + F0 + k], W[(224 + k) * 64 + o], a);
    float v = sprow[o] + softplus_f(a);
    spout[r * 64 + o] = v;
    atomicAdd(&sums_out[(r < 512 ? 0 : 64) + o], v);
}

// final layer + fin projection + residual x
__global__ __launch_bounds__(256) void sp_final_kernel(
    const float* __restrict__ spin, const float* __restrict__ W,
    const float* __restrict__ b, const float* __restrict__ sums_in,
    const float* __restrict__ Srow, const float* __restrict__ Scol,
    const float* __restrict__ x, const float* __restrict__ finw, const float* __restrict__ finb,
    float* __restrict__ out)
{
    __shared__ float uv[64];
    __shared__ float sb[4][64];
    int t = threadIdx.x;
    int ty = t >> 6, o = t & 63;
    if (t < 64) {
        const float ns = 1.0f / 512.0f;
        float a2 = b[t];
        #pragma unroll 8
        for (int k = 0; k < 64; ++k) a2 = fmaf(sums_in[k] * ns, W[(64 + k) * 64 + t], a2);
        #pragma unroll 8
        for (int k = 0; k < 64; ++k) a2 = fmaf(sums_in[64 + k] * ns, W[(128 + k) * 64 + t], a2);
        uv[t] = a2;
    }
    __syncthreads();
    int r = blockIdx.x * 4 + ty;
    float a = uv[o];
    const float* sprow = spin + r * 64;
    #pragma unroll 8
    for (int k = 0; k < 64; ++k) a = fmaf(sprow[k], W[k * 64 + o], a);
    #pragma unroll 8
    for (int k = 0; k < 32; ++k) a = fmaf(Srow[r * NF + 72 + k], W[(192 + k) * 64 + o], a);
    #pragma unroll 8
    for (int k = 0; k < 32; ++k) a = fmaf(Scol[r * NF + 72 + k], W[(224 + k) * 64 + o], a);
    sb[ty][o] = sprow[o] + softplus_f(a);
    __syncthreads();
    if (t < 12) {
        int rr = t / 3, d = t - rr * 3;
        int row = blockIdx.x * 4 + rr;
        float acc = x[row * 3 + d] + finb[d];
        #pragma unroll
        for (int k = 0; k < 64; ++k) acc = fmaf(sb[rr][k], finw[k * 3 + d], acc);
        out[row * 3 + d] = acc;
    }
}

extern "C" void kernel_launch(void* const* d_in, const int* in_sizes, int n_in,
                              void* d_out, int out_size, void* d_ws, size_t ws_size,
                              hipStream_t stream)
{
    (void)in_sizes; (void)n_in; (void)out_size; (void)ws_size;
    const float* x     = (const float*)d_in[0];
    const float* sp_w0 = (const float*)d_in[1];
    const float* sp_b0 = (const float*)d_in[2];
    const float* sp_w  = (const float*)d_in[3];
    const float* sp_b  = (const float*)d_in[4];
    const float* tp_w0 = (const float*)d_in[5];
    const float* tp_b0 = (const float*)d_in[6];
    const float* tp_w  = (const float*)d_in[7];
    const float* tp_b  = (const float*)d_in[8];
    const float* fin_w = (const float*)d_in[9];
    const float* fin_b = (const float*)d_in[10];
    float* out = (float*)d_out;
    float* ws  = (float*)d_ws;

    float* ws_rs = ws;                          // 32*1024*NF  (13.6 MB)
    float* ws_cs = ws_rs + 32 * NPART * NF;     // 16*1024*NF  (6.8 MB)
    float* Srow  = ws_cs + 16 * NPART * NF;     // 1024*NF
    float* Scol  = Srow + NPART * NF;           // 1024*NF
    float* sums0 = Scol + NPART * NF;           // 128 (zeroed by reduce_kernel)
    float* sums1 = sums0 + 128;                 // 128
    float* sums2 = sums1 + 128;                 // 128
    float* spA   = sums2 + 128;                 // 1024*64
    float* spB   = spA + NPART * 64;            // 1024*64
    float* spC   = spB + NPART * 64;            // 1024*64

    pair_kernel<<<dim3(16, 32), 256, 0, stream>>>(x, tp_w0, tp_b0, tp_w, tp_b, ws_rs, ws_cs);
    reduce_kernel<<<(NPART * NF + 255) / 256, 256, 0, stream>>>(ws_rs, ws_cs, Srow, Scol, sums0);
    sp_layer0_kernel<<<256, 256, 0, stream>>>(sp_w0, sp_b0, Srow, Scol, spA, sums0);
    sp_layer_kernel<<<256, 256, 0, stream>>>(spA, sp_w + 0 * 256 * 64, sp_b + 0 * 64,
                                             sums0, Srow, Scol, 8, spB, sums1);
    sp_layer_kernel<<<256, 256, 0, stream>>>(spB, sp_w + 1 * 256 * 64, sp_b + 1 * 64,
                                             sums1, Srow, Scol, 40, spC, sums2);
    sp_final_kernel<<<256, 256, 0, stream>>>(spC, sp_w + 2 * 256 * 64, sp_b + 2 * 64,
                                             sums2, Srow, Scol, x, fin_w, fin_b, out);
}